// Round 7
// baseline (438.202 us; speedup 1.0000x reference)
//
#include <hip/hip_runtime.h>
#include <hip/hip_bf16.h>
#include <math.h>

// Problem: T=1024, B=4, H=16, D=64, C=1024.
#define T_SEQ 1024
#define NB 4
#define NH 16
#define DD 64
#define CC 1024

typedef __attribute__((ext_vector_type(8))) short short8;   // 8 x bf16 (4 VGPR)
typedef __attribute__((ext_vector_type(4))) float floatx4;  // MFMA C/D
typedef __attribute__((ext_vector_type(4))) unsigned short ushort4v;

#define MFMA(a, b, c) __builtin_amdgcn_mfma_f32_16x16x32_bf16((a), (b), (c), 0, 0, 0)

__device__ inline float bf2f(unsigned short u) {
  union { unsigned int i; float f; } c; c.i = ((unsigned int)u) << 16; return c.f;
}
__device__ inline unsigned short f2bf(float x) {
  union { float f; unsigned int i; } c; c.f = x;
  unsigned int u = c.i;
  u += 0x7fff + ((u >> 16) & 1);   // RNE (inputs are finite)
  return (unsigned short)(u >> 16);
}

// async global->LDS, 16B per lane; LDS dest = wave-uniform base + lane*16
__device__ __forceinline__ void gload_lds16(const void* g, void* l) {
  __builtin_amdgcn_global_load_lds(
      (const __attribute__((address_space(1))) unsigned int*)g,
      (__attribute__((address_space(3))) unsigned int*)l, 16, 0, 0);
}

// ---------------------------------------------------------------------------
// Convert pass: fp32 -> bf16 for q/k/v inputs, pos_emb (padded to 2048 rows),
// and the 5 weight matrices. One vec8 per thread.
// ---------------------------------------------------------------------------
__global__ __launch_bounds__(256) void convert_kernel(
    const float* __restrict__ q, const float* __restrict__ k,
    const float* __restrict__ v, const float* __restrict__ pe_in,
    const float* __restrict__ wq, const float* __restrict__ wk,
    const float* __restrict__ wv, const float* __restrict__ wp,
    const float* __restrict__ wo,
    unsigned short* __restrict__ qo, unsigned short* __restrict__ ko,
    unsigned short* __restrict__ vo, unsigned short* __restrict__ po,
    unsigned short* __restrict__ wqo, unsigned short* __restrict__ wko,
    unsigned short* __restrict__ wvo, unsigned short* __restrict__ wpo,
    unsigned short* __restrict__ woo)
{
  const int i = blockIdx.x * 256 + threadIdx.x;  // vec8 index
  const float* src; unsigned short* dst; int off;
  if      (i < 524288)  { src = q;     dst = qo;  off = i; }
  else if (i < 1048576) { src = k;     dst = ko;  off = i - 524288; }
  else if (i < 1572864) { src = v;     dst = vo;  off = i - 1048576; }
  else if (i < 1834880) { src = pe_in; dst = po;  off = i - 1572864; }
  else if (i < 1965952) { src = wq;    dst = wqo; off = i - 1834880; }
  else if (i < 2097024) { src = wk;    dst = wko; off = i - 1965952; }
  else if (i < 2228096) { src = wv;    dst = wvo; off = i - 2097024; }
  else if (i < 2359168) { src = wp;    dst = wpo; off = i - 2228096; }
  else if (i < 2490240) { src = wo;    dst = woo; off = i - 2359168; }
  else {  // zero-fill pos_emb pad row 2047 (128 vec8 = 1024 elems)
    const int j = i - 2490240;
    *(short8*)&po[2047 * 1024 + j * 8] = (short8){0, 0, 0, 0, 0, 0, 0, 0};
    return;
  }
  const float4 a0 = *(const float4*)(src + (size_t)off * 8);
  const float4 a1 = *(const float4*)(src + (size_t)off * 8 + 4);
  short8 val = (short8){(short)f2bf(a0.x), (short)f2bf(a0.y), (short)f2bf(a0.z), (short)f2bf(a0.w),
                        (short)f2bf(a1.x), (short)f2bf(a1.y), (short)f2bf(a1.z), (short)f2bf(a1.w)};
  *(short8*)&dst[(size_t)off * 8] = val;
}

// ---------------------------------------------------------------------------
// m97-pattern bf16 MFMA GEMM core: C[m,n] = sum_k A[m,k]*W[n,k] (+bias[n])
// ---------------------------------------------------------------------------
template <int OUT_BF16>
__device__ __forceinline__ void gemm_core(
    const unsigned short* __restrict__ A, const unsigned short* __restrict__ Wt,
    const float* __restrict__ bias, void* __restrict__ Cv,
    unsigned short* As, unsigned short* Bs, int N, int K, int bm, int bn)
{
  const int tid = threadIdx.x;
  const int lane = tid & 63;
  const int w = tid >> 6;
  const int l15 = lane & 15, quad = lane >> 4;
  const int rw = (w >> 1) * 64, cw = (w & 1) * 64;

  floatx4 acc[4][4];
#pragma unroll
  for (int i = 0; i < 4; ++i)
#pragma unroll
    for (int j = 0; j < 4; ++j) acc[i][j] = (floatx4){0.f, 0.f, 0.f, 0.f};

  const int lrow = lane >> 2, lcol = (lane & 3) * 8;
  const unsigned short* Ag = A + (size_t)(bm + w * 32 + lrow) * K + lcol;
  const unsigned short* Wg = Wt + (size_t)(bn + w * 32 + lrow) * K + lcol;
  unsigned short* AsW = As + w * 1024;
  unsigned short* BsW = Bs + w * 1024;

  for (int k0 = 0; k0 < K; k0 += 32) {
    gload_lds16(Ag + k0, AsW);
    gload_lds16(Ag + 16 * K + k0, AsW + 512);
    gload_lds16(Wg + k0, BsW);
    gload_lds16(Wg + 16 * K + k0, BsW + 512);
    __syncthreads();

    short8 af[4], bfr[4];
#pragma unroll
    for (int i = 0; i < 4; ++i)
      af[i] = *(short8*)&As[(rw + i * 16 + l15) * 32 + quad * 8];
#pragma unroll
    for (int j = 0; j < 4; ++j)
      bfr[j] = *(short8*)&Bs[(cw + j * 16 + l15) * 32 + quad * 8];
#pragma unroll
    for (int i = 0; i < 4; ++i)
#pragma unroll
      for (int j = 0; j < 4; ++j)
        acc[i][j] = MFMA(af[i], bfr[j], acc[i][j]);
    __syncthreads();
  }

#pragma unroll
  for (int j = 0; j < 4; ++j) {
    const int col = bn + cw + j * 16 + l15;
    const float bj = bias ? bias[col] : 0.f;
#pragma unroll
    for (int i = 0; i < 4; ++i) {
      const int row0 = bm + rw + i * 16 + quad * 4;
#pragma unroll
      for (int reg = 0; reg < 4; ++reg) {
        const float v = acc[i][j][reg] + bj;
        if (OUT_BF16)
          ((unsigned short*)Cv)[(size_t)(row0 + reg) * N + col] = f2bf(v);
        else
          ((float*)Cv)[(size_t)(row0 + reg) * N + col] = v;
      }
    }
  }
}

struct GemmJob { const unsigned short* A; const unsigned short* Wt;
                 const float* bias; unsigned short* C; int mtiles; };
struct GemmJobs { GemmJob j[4]; };

// Fused Q,K,V,P projection GEMMs (z picks job; P has 16 m-tiles).
__global__ __launch_bounds__(256) void gemm_qkvp(GemmJobs jobs) {
  __shared__ __align__(16) unsigned short As[128 * 32];
  __shared__ __align__(16) unsigned short Bs[128 * 32];
  GemmJob jb = jobs.j[blockIdx.z];
  if ((int)blockIdx.y >= jb.mtiles) return;
  gemm_core<1>(jb.A, jb.Wt, jb.bias, jb.C, As, Bs, 1024, 1024,
               blockIdx.y * 128, blockIdx.x * 128);
}

template <int OUT_BF16>
__global__ __launch_bounds__(256) void gemm_one(
    const unsigned short* __restrict__ A, const unsigned short* __restrict__ Wt,
    const float* __restrict__ bias, void* __restrict__ Cv) {
  __shared__ __align__(16) unsigned short As[128 * 32];
  __shared__ __align__(16) unsigned short Bs[128 * 32];
  gemm_core<OUT_BF16>(A, Wt, bias, Cv, As, Bs, 1024, 1024,
                      blockIdx.y * 128, blockIdx.x * 128);
}

// ---------------------------------------------------------------------------
// Transpose V per (b,h): vb rows (t*4+b), cols h*64+d  ->  vT[b][h][d][t]
// ---------------------------------------------------------------------------
__global__ __launch_bounds__(256) void transpose_v(
    const unsigned short* __restrict__ vb, unsigned short* __restrict__ vT)
{
  __shared__ __align__(16) unsigned short Lt[64 * 136];
  const int t0 = blockIdx.x * 128;
  const int h = blockIdx.y, b = blockIdx.z;
  const int tid = threadIdx.x;

#pragma unroll
  for (int cc = 0; cc < 4; ++cc) {
    const int idx = tid + cc * 256;
    const int r = idx >> 3, pc = idx & 7;
    short8 val = *(const short8*)(vb + ((size_t)((t0 + r) * 4 + b)) * 1024 + h * 64 + pc * 8);
#pragma unroll
    for (int e = 0; e < 8; ++e)
      Lt[(pc * 8 + e) * 136 + r] = (unsigned short)val[e];
  }
  __syncthreads();
#pragma unroll
  for (int cc = 0; cc < 4; ++cc) {
    const int idx = tid + cc * 256;
    const int d = idx >> 4, tc = idx & 15;
    short8 v2 = *(short8*)&Lt[d * 136 + tc * 8];
    *(short8*)(vT + ((size_t)((b * 16 + h) * 64 + d)) * 1024 + t0 + tc * 8) = v2;
  }
}

// ---------------------------------------------------------------------------
// Precompute rank-1 bias dots: uk[(b*16+h)*1024+s] = pbu[h]·k[b,s,h]
//                              vp[idx*16+h]        = pbv[h]·p[idx,h]
// ---------------------------------------------------------------------------
__global__ __launch_bounds__(256) void precompute_kernel(
    const unsigned short* __restrict__ kb, const unsigned short* __restrict__ pb,
    const float* __restrict__ pbu, const float* __restrict__ pbv,
    float* __restrict__ uk, float* __restrict__ vp)
{
  const int i = blockIdx.x * 256 + threadIdx.x;
  if (i < 65536) {
    const int b = i >> 14, h = (i >> 10) & 15, s = i & 1023;
    const unsigned short* kr = kb + ((size_t)(s * 4 + b)) * 1024 + h * 64;
    const float* ur = pbu + h * 64;
    float sum = 0.f;
#pragma unroll
    for (int c = 0; c < 8; ++c) {
      short8 kv = *(const short8*)(kr + c * 8);
#pragma unroll
      for (int e = 0; e < 8; ++e) sum += bf2f((unsigned short)kv[e]) * ur[c * 8 + e];
    }
    uk[i] = sum;
  } else if (i < 98304) {
    const int j = i - 65536;
    const int idx = j >> 4, h = j & 15;
    const unsigned short* pr = pb + (size_t)idx * 1024 + h * 64;
    const float* vr = pbv + h * 64;
    float sum = 0.f;
#pragma unroll
    for (int c = 0; c < 8; ++c) {
      short8 pv = *(const short8*)(pr + c * 8);
#pragma unroll
      for (int e = 0; e < 8; ++e) sum += bf2f((unsigned short)pv[e]) * vr[c * 8 + e];
    }
    vp[(idx << 4) + h] = sum;
  }
}

// ---------------------------------------------------------------------------
// Fused rel-pos MFMA attention v4 — BARRIER-FREE inner loop.
// Each wave owns 16 q-rows x all 128 s of the tile:
//   - softmax reductions wave-local (shfl_xor 16/32)
//   - P round-trip via wave-private LDS strip (lgkmcnt only)
//   - BD skew via wave-private LDS strip, v.p bias folded at write
//   - uk/vp staged once before the loop (single __syncthreads total)
// Score St[s][t] C-layout: s=quad*4+reg, t=l15. O C-layout: t=quad*4+reg,
// d=l15; alpha/l cross layouts via ds_bpermute (wave-local).
// ---------------------------------------------------------------------------
__global__ __launch_bounds__(256) void attn_kernel(
    const unsigned short* __restrict__ qb, const unsigned short* __restrict__ kb,
    const unsigned short* __restrict__ pb, const unsigned short* __restrict__ vT,
    const float* __restrict__ uk, const float* __restrict__ vp,
    unsigned short* __restrict__ xb)
{
  __shared__ __align__(16) float BDs[4][16][164];          // [wave][t][jl] fp32
  __shared__ __align__(16) unsigned short Pw[4][16][136];  // [wave][t][s] bf16
  __shared__ __align__(16) float uk_full[1024];
  __shared__ __align__(16) float vp_full[1104];

  const int tid = threadIdx.x;
  const int lane = tid & 63;
  const int w = tid >> 6;
  const int l15 = lane & 15, quad = lane >> 4;

  // XCD swizzle: cluster the 16 q-tiles of one (b,h) on one XCD.
  const int flat = blockIdx.x + (blockIdx.y << 4) + (blockIdx.z << 8);
  const int x8 = flat & 7, s8 = flat >> 3;
  const int hb = x8 * 8 + (s8 >> 4);
  const int t0 = (s8 & 15) * 64;
  const int b = hb >> 4, h = hb & 15;

  // stage uk (full row) + vp (block window) once
  for (int i = tid; i < 1024; i += 256) uk_full[i] = uk[((b * 16 + h) << 10) + i];
  const int gbase = 960 - t0;
  for (int i = tid; i < 1104; i += 256) {
    int g = gbase + i; g = g > 2047 ? 2047 : g;
    vp_full[i] = vp[(g << 4) + h];
  }
  __syncthreads();  // only block-wide barrier in this kernel

  const int tw = t0 + w * 16;  // wave's first t row (global)

  // Q fragments (B-operand): n = t = tw + l15, k = d
  short8 qf[2];
#pragma unroll
  for (int kk = 0; kk < 2; ++kk)
    qf[kk] = *(const short8*)(qb + ((size_t)((tw + l15) * 4 + b)) * 1024 + h * 64 + kk * 32 + quad * 8);

  floatx4 of[4];  // O[t=quad*4+reg][d=dt*16+l15]
#pragma unroll
  for (int dt = 0; dt < 4; ++dt) of[dt] = (floatx4){0.f, 0.f, 0.f, 0.f};
  float m_ln = -3.0e38f, l_ln = 0.f;  // per-lane row state for t = tw + l15

  float* BDw = &BDs[w][0][0];
  unsigned short* Pww = &Pw[w][0][0];
  const unsigned short* vTh = vT + ((size_t)((b * 16 + h) * 64)) * 1024;

  for (int s0 = 0; s0 < 1024; s0 += 128) {
    const int pbase = s0 - t0 + 1008 - w * 16;  // global p row of jl=0 (may run 16 past 2047: memory-safe, never read)
    const int vbase = s0 - w * 16 + 48;         // vp_full index of jl=0

    // ---- BD skew MFMAs -> wave-private BDs (vp folded in) ----
#pragma unroll
    for (int jt = 0; jt < 10; ++jt) {
      const unsigned short* pr = pb + (size_t)(pbase + jt * 16 + l15) * 1024 + h * 64;
      short8 pf0 = *(const short8*)(pr + quad * 8);
      short8 pf1 = *(const short8*)(pr + 32 + quad * 8);
      floatx4 z = (floatx4){0.f, 0.f, 0.f, 0.f};
      z = MFMA(pf0, qf[0], z);
      z = MFMA(pf1, qf[1], z);
      const float4 vpv = *(const float4*)&vp_full[vbase + jt * 16 + quad * 4];
      float4 o;
      o.x = z[0] + vpv.x; o.y = z[1] + vpv.y; o.z = z[2] + vpv.z; o.w = z[3] + vpv.w;
      *(float4*)&BDw[l15 * 164 + jt * 16 + quad * 4] = o;
    }

    // ---- AC MFMAs (K fragments direct from global) ----
    floatx4 st[8];
#pragma unroll
    for (int stile = 0; stile < 8; ++stile) {
      const int srow = s0 + stile * 16 + l15;
      const unsigned short* kr = kb + ((size_t)(srow * 4 + b)) * 1024 + h * 64;
      short8 kf0 = *(const short8*)(kr + quad * 8);
      short8 kf1 = *(const short8*)(kr + 32 + quad * 8);
      floatx4 z = (floatx4){0.f, 0.f, 0.f, 0.f};
      z = MFMA(kf0, qf[0], z);
      z = MFMA(kf1, qf[1], z);
      st[stile] = z;
    }

    // ---- score assembly + wave-local max (reads own BDs strip) ----
    float lmax = -3.0e38f;
#pragma unroll
    for (int stile = 0; stile < 8; ++stile) {
      const float4 uk4 = *(const float4*)&uk_full[s0 + stile * 16 + quad * 4];
      const int jb = stile * 16 + quad * 4 - l15 + 15;
#pragma unroll
      for (int reg = 0; reg < 4; ++reg) {
        const float ukr = reg == 0 ? uk4.x : (reg == 1 ? uk4.y : (reg == 2 ? uk4.z : uk4.w));
        float v = 0.125f * (st[stile][reg] + BDw[l15 * 164 + jb + reg] + ukr);
        st[stile][reg] = v;
        lmax = fmaxf(lmax, v);
      }
    }
    lmax = fmaxf(lmax, __shfl_xor(lmax, 16));
    lmax = fmaxf(lmax, __shfl_xor(lmax, 32));
    const float mn = fmaxf(m_ln, lmax);
    const float alpha = __expf(m_ln - mn);
    m_ln = mn;

    // ---- exp, Pw write (wave-private), sum ----
    float lsum = 0.f;
#pragma unroll
    for (int stile = 0; stile < 8; ++stile) {
      float p0 = __expf(st[stile][0] - mn);
      float p1 = __expf(st[stile][1] - mn);
      float p2 = __expf(st[stile][2] - mn);
      float p3 = __expf(st[stile][3] - mn);
      lsum += p0 + p1 + p2 + p3;
      ushort4v pk = (ushort4v){f2bf(p0), f2bf(p1), f2bf(p2), f2bf(p3)};
      *(ushort4v*)&Pww[l15 * 136 + stile * 16 + quad * 4] = pk;
    }
    lsum += __shfl_xor(lsum, 16);
    lsum += __shfl_xor(lsum, 32);
    l_ln = l_ln * alpha + lsum;

    // ---- O rescale (alpha for t=quad*4+reg via bpermute) + PV MFMAs ----
#pragma unroll
    for (int reg = 0; reg < 4; ++reg) {
      const float ar = __shfl(alpha, quad * 4 + reg);
#pragma unroll
      for (int dt = 0; dt < 4; ++dt) of[dt][reg] *= ar;
    }
#pragma unroll
    for (int kk = 0; kk < 4; ++kk) {
      const short8 pa = *(short8*)&Pww[l15 * 136 + kk * 32 + quad * 8];
#pragma unroll
      for (int dt = 0; dt < 4; ++dt) {
        const short8 vf = *(const short8*)(vTh + (size_t)(dt * 16 + l15) * 1024 + s0 + kk * 32 + quad * 8);
        of[dt] = MFMA(pa, vf, of[dt]);
      }
    }
  }

  // ---- finalize: l for rows t=quad*4+reg via bpermute ----
#pragma unroll
  for (int reg = 0; reg < 4; ++reg) {
    const float lr = __shfl(l_ln, quad * 4 + reg);
    const float il = 1.f / lr;
    const int t = tw + quad * 4 + reg;
#pragma unroll
    for (int dt = 0; dt < 4; ++dt) {
      const int d = dt * 16 + l15;
      xb[((size_t)(t * 4 + b)) * 1024 + h * 64 + d] = f2bf(of[dt][reg] * il);
    }
  }
}

// ---------------------------------------------------------------------------
extern "C" void kernel_launch(void* const* d_in, const int* in_sizes, int n_in,
                              void* d_out, int out_size, void* d_ws, size_t ws_size,
                              hipStream_t stream) {
  const float* query   = (const float*)d_in[0];
  const float* key_    = (const float*)d_in[1];
  const float* value   = (const float*)d_in[2];
  const float* pos_emb = (const float*)d_in[3];
  const float* Wq  = (const float*)d_in[4];
  const float* bq  = (const float*)d_in[5];
  const float* Wk  = (const float*)d_in[6];
  const float* bk  = (const float*)d_in[7];
  const float* Wv  = (const float*)d_in[8];
  const float* bv  = (const float*)d_in[9];
  const float* Wp  = (const float*)d_in[10];
  const float* Wo  = (const float*)d_in[11];
  const float* bo  = (const float*)d_in[12];
  const float* pbu = (const float*)d_in[13];
  const float* pbv = (const float*)d_in[14];
  float* out = (float*)d_out;

  // workspace (ushort elements), ~69.6 MB total
  unsigned short* U = (unsigned short*)d_ws;
  unsigned short* qin = U;                   // bf16 query   (later: attn out xb)
  unsigned short* kin = U + 4194304;         // bf16 key
  unsigned short* vin = U + 8388608;         // bf16 value
  unsigned short* pe  = U + 12582912;        // bf16 pos_emb 2048 rows (later: vTb)
  unsigned short* wq  = U + 14680064;
  unsigned short* wk  = U + 15728640;
  unsigned short* wv  = U + 16777216;
  unsigned short* wp  = U + 17825792;
  unsigned short* wo  = U + 18874368;
  unsigned short* qb  = U + 19922944;        // Q proj
  unsigned short* kb  = U + 24117248;        // K proj
  unsigned short* pb  = U + 28311552;        // P proj (2048 rows; +16 OOB rows read harmlessly into vpo)
  unsigned short* vpo = U + 30408704;        // V proj
  unsigned short* vTb = pe;                  // aliases pe+wq+wk (dead after projections)
  unsigned short* xb  = qin;                 // attn out (qin dead after projections)
  float* fbase = (float*)(U + 34603008);
  float* uk = fbase;                         // 65536 floats
  float* vp = fbase + 65536;                 // 32768 floats

  const dim3 blk(256);

  // 1. convert everything to bf16 (one HBM-bound pass)
  convert_kernel<<<dim3(9728), blk, 0, stream>>>(
      query, key_, value, pos_emb, Wq, Wk, Wv, Wp, Wo,
      qin, kin, vin, pe, wq, wk, wv, wp, wo);

  // 2. fused Q,K,V,P projections (896 active blocks)
  GemmJobs jobs;
  jobs.j[0] = GemmJob{qin, wq, bq, qb, 32};
  jobs.j[1] = GemmJob{kin, wk, bk, kb, 32};
  jobs.j[2] = GemmJob{vin, wv, bv, vpo, 32};
  jobs.j[3] = GemmJob{pe,  wp, nullptr, pb, 16};
  gemm_qkvp<<<dim3(8, 32, 4), blk, 0, stream>>>(jobs);

  // 3. transpose V for PV MFMA B-operand (writes over dead pe/wq/wk)
  transpose_v<<<dim3(8, 16, 4), blk, 0, stream>>>(vpo, vTb);

  // 4. rank-1 bias dots
  precompute_kernel<<<dim3(384), blk, 0, stream>>>(kb, pb, pbu, pbv, uk, vp);

  // 5. fused attention (writes into dead qin buffer)
  attn_kernel<<<dim3(16, 16, 4), blk, 0, stream>>>(qb, kb, pb, vTb, uk, vp, xb);

  // 6. output projection -> fp32 d_out
  gemm_one<0><<<dim3(8, 32), blk, 0, stream>>>(xb, wo, bo, out);
}

// Round 8
// 351.177 us; speedup vs baseline: 1.2478x; 1.2478x over previous
//
#include <hip/hip_runtime.h>
#include <hip/hip_bf16.h>
#include <math.h>

// Problem: T=1024, B=4, H=16, D=64, C=1024.
#define T_SEQ 1024
#define NB 4
#define NH 16
#define DD 64
#define CC 1024

typedef __attribute__((ext_vector_type(8))) short short8;   // 8 x bf16 (4 VGPR)
typedef __attribute__((ext_vector_type(4))) float floatx4;  // MFMA C/D
typedef __attribute__((ext_vector_type(4))) unsigned short ushort4v;

#define MFMA(a, b, c) __builtin_amdgcn_mfma_f32_16x16x32_bf16((a), (b), (c), 0, 0, 0)

__device__ inline float bf2f(unsigned short u) {
  union { unsigned int i; float f; } c; c.i = ((unsigned int)u) << 16; return c.f;
}
__device__ inline unsigned short f2bf(float x) {
  union { float f; unsigned int i; } c; c.f = x;
  unsigned int u = c.i;
  u += 0x7fff + ((u >> 16) & 1);   // RNE (inputs are finite)
  return (unsigned short)(u >> 16);
}

// async global->LDS, 16B per lane; LDS dest = wave-uniform base + lane*16
__device__ __forceinline__ void gload_lds16(const void* g, void* l) {
  __builtin_amdgcn_global_load_lds(
      (const __attribute__((address_space(1))) unsigned int*)g,
      (__attribute__((address_space(3))) unsigned int*)l, 16, 0, 0);
}

// ---------------------------------------------------------------------------
// Convert pass: fp32 -> bf16 for q/k/v inputs, pos_emb (padded to 2048 rows),
// and the 5 weight matrices. One vec8 per thread.
// ---------------------------------------------------------------------------
__global__ __launch_bounds__(256) void convert_kernel(
    const float* __restrict__ q, const float* __restrict__ k,
    const float* __restrict__ v, const float* __restrict__ pe_in,
    const float* __restrict__ wq, const float* __restrict__ wk,
    const float* __restrict__ wv, const float* __restrict__ wp,
    const float* __restrict__ wo,
    unsigned short* __restrict__ qo, unsigned short* __restrict__ ko,
    unsigned short* __restrict__ vo, unsigned short* __restrict__ po,
    unsigned short* __restrict__ wqo, unsigned short* __restrict__ wko,
    unsigned short* __restrict__ wvo, unsigned short* __restrict__ wpo,
    unsigned short* __restrict__ woo)
{
  const int i = blockIdx.x * 256 + threadIdx.x;  // vec8 index
  const float* src; unsigned short* dst; int off;
  if      (i < 524288)  { src = q;     dst = qo;  off = i; }
  else if (i < 1048576) { src = k;     dst = ko;  off = i - 524288; }
  else if (i < 1572864) { src = v;     dst = vo;  off = i - 1048576; }
  else if (i < 1834880) { src = pe_in; dst = po;  off = i - 1572864; }
  else if (i < 1965952) { src = wq;    dst = wqo; off = i - 1834880; }
  else if (i < 2097024) { src = wk;    dst = wko; off = i - 1965952; }
  else if (i < 2228096) { src = wv;    dst = wvo; off = i - 2097024; }
  else if (i < 2359168) { src = wp;    dst = wpo; off = i - 2228096; }
  else if (i < 2490240) { src = wo;    dst = woo; off = i - 2359168; }
  else {  // zero-fill pos_emb pad row 2047 (128 vec8 = 1024 elems)
    const int j = i - 2490240;
    *(short8*)&po[2047 * 1024 + j * 8] = (short8){0, 0, 0, 0, 0, 0, 0, 0};
    return;
  }
  const float4 a0 = *(const float4*)(src + (size_t)off * 8);
  const float4 a1 = *(const float4*)(src + (size_t)off * 8 + 4);
  short8 val = (short8){(short)f2bf(a0.x), (short)f2bf(a0.y), (short)f2bf(a0.z), (short)f2bf(a0.w),
                        (short)f2bf(a1.x), (short)f2bf(a1.y), (short)f2bf(a1.z), (short)f2bf(a1.w)};
  *(short8*)&dst[(size_t)off * 8] = val;
}

// ---------------------------------------------------------------------------
// m97-pattern bf16 MFMA GEMM core: C[m,n] = sum_k A[m,k]*W[n,k] (+bias[n])
// ---------------------------------------------------------------------------
template <int OUT_BF16>
__device__ __forceinline__ void gemm_core(
    const unsigned short* __restrict__ A, const unsigned short* __restrict__ Wt,
    const float* __restrict__ bias, void* __restrict__ Cv,
    unsigned short* As, unsigned short* Bs, int N, int K, int bm, int bn)
{
  const int tid = threadIdx.x;
  const int lane = tid & 63;
  const int w = tid >> 6;
  const int l15 = lane & 15, quad = lane >> 4;
  const int rw = (w >> 1) * 64, cw = (w & 1) * 64;

  floatx4 acc[4][4];
#pragma unroll
  for (int i = 0; i < 4; ++i)
#pragma unroll
    for (int j = 0; j < 4; ++j) acc[i][j] = (floatx4){0.f, 0.f, 0.f, 0.f};

  const int lrow = lane >> 2, lcol = (lane & 3) * 8;
  const unsigned short* Ag = A + (size_t)(bm + w * 32 + lrow) * K + lcol;
  const unsigned short* Wg = Wt + (size_t)(bn + w * 32 + lrow) * K + lcol;
  unsigned short* AsW = As + w * 1024;
  unsigned short* BsW = Bs + w * 1024;

  for (int k0 = 0; k0 < K; k0 += 32) {
    gload_lds16(Ag + k0, AsW);
    gload_lds16(Ag + 16 * K + k0, AsW + 512);
    gload_lds16(Wg + k0, BsW);
    gload_lds16(Wg + 16 * K + k0, BsW + 512);
    __syncthreads();

    short8 af[4], bfr[4];
#pragma unroll
    for (int i = 0; i < 4; ++i)
      af[i] = *(short8*)&As[(rw + i * 16 + l15) * 32 + quad * 8];
#pragma unroll
    for (int j = 0; j < 4; ++j)
      bfr[j] = *(short8*)&Bs[(cw + j * 16 + l15) * 32 + quad * 8];
#pragma unroll
    for (int i = 0; i < 4; ++i)
#pragma unroll
      for (int j = 0; j < 4; ++j)
        acc[i][j] = MFMA(af[i], bfr[j], acc[i][j]);
    __syncthreads();
  }

#pragma unroll
  for (int j = 0; j < 4; ++j) {
    const int col = bn + cw + j * 16 + l15;
    const float bj = bias ? bias[col] : 0.f;
#pragma unroll
    for (int i = 0; i < 4; ++i) {
      const int row0 = bm + rw + i * 16 + quad * 4;
#pragma unroll
      for (int reg = 0; reg < 4; ++reg) {
        const float v = acc[i][j][reg] + bj;
        if (OUT_BF16)
          ((unsigned short*)Cv)[(size_t)(row0 + reg) * N + col] = f2bf(v);
        else
          ((float*)Cv)[(size_t)(row0 + reg) * N + col] = v;
      }
    }
  }
}

struct GemmJob { const unsigned short* A; const unsigned short* Wt;
                 const float* bias; unsigned short* C; int mtiles; };
struct GemmJobs { GemmJob j[4]; };

// Fused Q,K,V,P projection GEMMs (z picks job; P has 16 m-tiles).
__global__ __launch_bounds__(256) void gemm_qkvp(GemmJobs jobs) {
  __shared__ __align__(16) unsigned short As[128 * 32];
  __shared__ __align__(16) unsigned short Bs[128 * 32];
  GemmJob jb = jobs.j[blockIdx.z];
  if ((int)blockIdx.y >= jb.mtiles) return;
  gemm_core<1>(jb.A, jb.Wt, jb.bias, jb.C, As, Bs, 1024, 1024,
               blockIdx.y * 128, blockIdx.x * 128);
}

template <int OUT_BF16>
__global__ __launch_bounds__(256) void gemm_one(
    const unsigned short* __restrict__ A, const unsigned short* __restrict__ Wt,
    const float* __restrict__ bias, void* __restrict__ Cv) {
  __shared__ __align__(16) unsigned short As[128 * 32];
  __shared__ __align__(16) unsigned short Bs[128 * 32];
  gemm_core<OUT_BF16>(A, Wt, bias, Cv, As, Bs, 1024, 1024,
                      blockIdx.y * 128, blockIdx.x * 128);
}

// ---------------------------------------------------------------------------
// Transpose V per (b,h): vb rows (t*4+b), cols h*64+d  ->  vT[b][h][d][t]
// ---------------------------------------------------------------------------
__global__ __launch_bounds__(256) void transpose_v(
    const unsigned short* __restrict__ vb, unsigned short* __restrict__ vT)
{
  __shared__ __align__(16) unsigned short Lt[64 * 136];
  const int t0 = blockIdx.x * 128;
  const int h = blockIdx.y, b = blockIdx.z;
  const int tid = threadIdx.x;

#pragma unroll
  for (int cc = 0; cc < 4; ++cc) {
    const int idx = tid + cc * 256;
    const int r = idx >> 3, pc = idx & 7;
    short8 val = *(const short8*)(vb + ((size_t)((t0 + r) * 4 + b)) * 1024 + h * 64 + pc * 8);
#pragma unroll
    for (int e = 0; e < 8; ++e)
      Lt[(pc * 8 + e) * 136 + r] = (unsigned short)val[e];
  }
  __syncthreads();
#pragma unroll
  for (int cc = 0; cc < 4; ++cc) {
    const int idx = tid + cc * 256;
    const int d = idx >> 4, tc = idx & 15;
    short8 v2 = *(short8*)&Lt[d * 136 + tc * 8];
    *(short8*)(vT + ((size_t)((b * 16 + h) * 64 + d)) * 1024 + t0 + tc * 8) = v2;
  }
}

// ---------------------------------------------------------------------------
// Precompute rank-1 bias dots: uk[(b*16+h)*1024+s] = pbu[h]·k[b,s,h]
//                              vp[idx*16+h]        = pbv[h]·p[idx,h]
// ---------------------------------------------------------------------------
__global__ __launch_bounds__(256) void precompute_kernel(
    const unsigned short* __restrict__ kb, const unsigned short* __restrict__ pb,
    const float* __restrict__ pbu, const float* __restrict__ pbv,
    float* __restrict__ uk, float* __restrict__ vp)
{
  const int i = blockIdx.x * 256 + threadIdx.x;
  if (i < 65536) {
    const int b = i >> 14, h = (i >> 10) & 15, s = i & 1023;
    const unsigned short* kr = kb + ((size_t)(s * 4 + b)) * 1024 + h * 64;
    const float* ur = pbu + h * 64;
    float sum = 0.f;
#pragma unroll
    for (int c = 0; c < 8; ++c) {
      short8 kv = *(const short8*)(kr + c * 8);
#pragma unroll
      for (int e = 0; e < 8; ++e) sum += bf2f((unsigned short)kv[e]) * ur[c * 8 + e];
    }
    uk[i] = sum;
  } else if (i < 98304) {
    const int j = i - 65536;
    const int idx = j >> 4, h = j & 15;
    const unsigned short* pr = pb + (size_t)idx * 1024 + h * 64;
    const float* vr = pbv + h * 64;
    float sum = 0.f;
#pragma unroll
    for (int c = 0; c < 8; ++c) {
      short8 pv = *(const short8*)(pr + c * 8);
#pragma unroll
      for (int e = 0; e < 8; ++e) sum += bf2f((unsigned short)pv[e]) * vr[c * 8 + e];
    }
    vp[(idx << 4) + h] = sum;
  }
}

// ---------------------------------------------------------------------------
// Fused rel-pos MFMA attention v5 = exact R4 structure (5 barriers, separate
// Pb/BDf, V loads in Phase 5) + software-pipelined K/P fragment prefetch:
// next iteration's K and P fragments are issued right after Phase 1 consumes
// the current ones, so their L2 latency hides behind Phases 2-5 + barriers.
// Register loads don't force vmcnt(0) at __syncthreads -> stay in flight.
// ---------------------------------------------------------------------------
__global__ __launch_bounds__(256) void attn_kernel(
    const unsigned short* __restrict__ qb, const unsigned short* __restrict__ kb,
    const unsigned short* __restrict__ pb, const unsigned short* __restrict__ vT,
    const float* __restrict__ uk, const float* __restrict__ vp,
    unsigned short* __restrict__ xb)
{
  __shared__ __align__(16) unsigned short Pb[64 * 136];  // P[t][s] bf16
  __shared__ __align__(16) float BDf[64 * 196];          // BD[t][jj] fp32
  __shared__ float uk_s[128], vp_w[192];
  __shared__ float pmax[2][64], psum[2][64];
  __shared__ float m_row[64], l_row[64], alpha_row[64];

  const int tid = threadIdx.x;
  const int lane = tid & 63;
  const int w = tid >> 6;
  const int l15 = lane & 15, quad = lane >> 4;
  const int th = w & 1, sh = w >> 1;

  // XCD swizzle: cluster the 16 q-tiles of one (b,h) on one XCD.
  const int flat = blockIdx.x + (blockIdx.y << 4) + (blockIdx.z << 8);
  const int x8 = flat & 7, s8 = flat >> 3;
  const int hb = x8 * 8 + (s8 >> 4);
  const int t0 = (s8 & 15) * 64;
  const int b = hb >> 4, h = hb & 15;

  // Q as MFMA B-operand: B[k=d][n=t], lane n=l15, k=quad*8+j. qf[ttile][kstep]
  short8 qf[2][2];
#pragma unroll
  for (int tt = 0; tt < 2; ++tt)
#pragma unroll
    for (int kk = 0; kk < 2; ++kk) {
      const int t = t0 + th * 32 + tt * 16 + l15;
      qf[tt][kk] = *(const short8*)(qb + ((size_t)(t * 4 + b)) * 1024 + h * 64 + kk * 32 + quad * 8);
    }

  floatx4 of[2][2];  // O[t-tile][d-tile], rows t=quad*4+reg, cols d=l15
#pragma unroll
  for (int i = 0; i < 2; ++i)
#pragma unroll
    for (int j = 0; j < 2; ++j) of[i][j] = (floatx4){0.f, 0.f, 0.f, 0.f};

  if (tid < 64) { m_row[tid] = -3.0e38f; l_row[tid] = 0.f; }
  __syncthreads();

  // per-wave fragment pointers (depend only on s0; same lane pattern each iter)
  const unsigned short* kbase = kb + ((size_t)((sh * 64 + l15) * 4 + b)) * 1024 + h * 64;
  const unsigned short* pbase0 = pb + ((size_t)(sh * 96 + l15)) * 1024 + h * 64;

  // prefetched fragments for the CURRENT iteration
  short8 kf[4][2], pf[6][2];
  {
    const int w0 = 0 - t0 + 960;
#pragma unroll
    for (int st4 = 0; st4 < 4; ++st4) {
      const unsigned short* kr = kbase + (size_t)(st4 * 16) * 4096;
      kf[st4][0] = *(const short8*)(kr + quad * 8);
      kf[st4][1] = *(const short8*)(kr + 32 + quad * 8);
    }
#pragma unroll
    for (int jt = 0; jt < 6; ++jt) {
      const unsigned short* pr = pbase0 + (size_t)(w0 + jt * 16) * 1024;
      pf[jt][0] = *(const short8*)(pr + quad * 8);
      pf[jt][1] = *(const short8*)(pr + 32 + quad * 8);
    }
  }

  for (int s0 = 0; s0 < 1024; s0 += 128) {
    const int w0 = s0 - t0 + 960;

    if (tid < 128) uk_s[tid] = uk[((b * 16 + h) << 10) + s0 + tid];
    if (tid < 192) vp_w[tid] = vp[(((size_t)(w0 + tid)) << 4) + h];

    // ---- Phase 1: BD MFMA (uses prefetched pf) + AC MFMA (uses kf) ----
#pragma unroll
    for (int jt = 0; jt < 6; ++jt) {
#pragma unroll
      for (int tt = 0; tt < 2; ++tt) {
        floatx4 z = (floatx4){0.f, 0.f, 0.f, 0.f};
        z = MFMA(pf[jt][0], qf[tt][0], z);
        z = MFMA(pf[jt][1], qf[tt][1], z);
        const int tloc = th * 32 + tt * 16 + l15;
        const int jjb = sh * 96 + jt * 16 + quad * 4;
        *(float4*)&BDf[tloc * 196 + jjb] = make_float4(z[0], z[1], z[2], z[3]);
      }
    }

    floatx4 st[4][2];
#pragma unroll
    for (int stile = 0; stile < 4; ++stile) {
#pragma unroll
      for (int tt = 0; tt < 2; ++tt) {
        floatx4 z = (floatx4){0.f, 0.f, 0.f, 0.f};
        z = MFMA(kf[stile][0], qf[tt][0], z);
        z = MFMA(kf[stile][1], qf[tt][1], z);
        st[stile][tt] = z;
      }
    }

    // ---- issue next-iteration K/P fragment loads (in flight across barriers) ----
    {
      const int s0n = (s0 + 128 < 1024) ? (s0 + 128) : 0;  // last iter: dummy reload
      const int w0n = s0n - t0 + 960;
#pragma unroll
      for (int st4 = 0; st4 < 4; ++st4) {
        const unsigned short* kr = kbase + (size_t)(s0n + st4 * 16) * 4096;
        kf[st4][0] = *(const short8*)(kr + quad * 8);
        kf[st4][1] = *(const short8*)(kr + 32 + quad * 8);
      }
#pragma unroll
      for (int jt = 0; jt < 6; ++jt) {
        const unsigned short* pr = pbase0 + (size_t)(w0n + jt * 16) * 1024;
        pf[jt][0] = *(const short8*)(pr + quad * 8);
        pf[jt][1] = *(const short8*)(pr + 32 + quad * 8);
      }
    }
    __syncthreads();  // B_a: BDf visible

    // ---- Phase 2: assemble scores + per-t local max ----
    float lmax[2] = {-3.0e38f, -3.0e38f};
#pragma unroll
    for (int stile = 0; stile < 4; ++stile)
#pragma unroll
      for (int tt = 0; tt < 2; ++tt) {
        const int tloc = th * 32 + tt * 16 + l15;
#pragma unroll
        for (int reg = 0; reg < 4; ++reg) {
          const int sloc = sh * 64 + stile * 16 + quad * 4 + reg;
          const int jj = sloc - tloc + 63;
          float v = 0.125f * (st[stile][tt][reg] + BDf[tloc * 196 + jj] +
                              uk_s[sloc] + vp_w[jj]);
          st[stile][tt][reg] = v;
          lmax[tt] = fmaxf(lmax[tt], v);
        }
      }
#pragma unroll
    for (int tt = 0; tt < 2; ++tt) {
      lmax[tt] = fmaxf(lmax[tt], __shfl_xor(lmax[tt], 16));
      lmax[tt] = fmaxf(lmax[tt], __shfl_xor(lmax[tt], 32));
    }
    if (quad == 0) {
      pmax[sh][th * 32 + l15] = lmax[0];
      pmax[sh][th * 32 + 16 + l15] = lmax[1];
    }
    __syncthreads();  // B_b

    // ---- Phase 3: per-row m/alpha update ----
    if (tid < 64) {
      const float mo = m_row[tid];
      const float mn = fmaxf(mo, fmaxf(pmax[0][tid], pmax[1][tid]));
      alpha_row[tid] = __expf(mo - mn);
      m_row[tid] = mn;
    }
    __syncthreads();  // B_c

    // ---- Phase 4: P=exp, Pb write, psum, O rescale ----
    float lsum[2] = {0.f, 0.f};
    float mt[2];
#pragma unroll
    for (int tt = 0; tt < 2; ++tt) mt[tt] = m_row[th * 32 + tt * 16 + l15];
#pragma unroll
    for (int stile = 0; stile < 4; ++stile)
#pragma unroll
      for (int tt = 0; tt < 2; ++tt) {
        float p0 = __expf(st[stile][tt][0] - mt[tt]);
        float p1 = __expf(st[stile][tt][1] - mt[tt]);
        float p2 = __expf(st[stile][tt][2] - mt[tt]);
        float p3 = __expf(st[stile][tt][3] - mt[tt]);
        lsum[tt] += p0 + p1 + p2 + p3;
        const int tloc = th * 32 + tt * 16 + l15;
        const int sb = sh * 64 + stile * 16 + quad * 4;
        ushort4v pk = (ushort4v){f2bf(p0), f2bf(p1), f2bf(p2), f2bf(p3)};
        *(ushort4v*)&Pb[tloc * 136 + sb] = pk;
      }
#pragma unroll
    for (int tt = 0; tt < 2; ++tt) {
      lsum[tt] += __shfl_xor(lsum[tt], 16);
      lsum[tt] += __shfl_xor(lsum[tt], 32);
    }
    if (quad == 0) {
      psum[sh][th * 32 + l15] = lsum[0];
      psum[sh][th * 32 + 16 + l15] = lsum[1];
    }
#pragma unroll
    for (int tt = 0; tt < 2; ++tt)
#pragma unroll
      for (int reg = 0; reg < 4; ++reg) {
        const float ar = alpha_row[th * 32 + tt * 16 + quad * 4 + reg];
        of[tt][0][reg] *= ar;
        of[tt][1][reg] *= ar;
      }
    __syncthreads();  // B_d

    // ---- Phase 5: l update + PV MFMA (V loads here, as R4) ----
    if (tid < 64)
      l_row[tid] = l_row[tid] * alpha_row[tid] + psum[0][tid] + psum[1][tid];
#pragma unroll
    for (int kk2 = 0; kk2 < 4; ++kk2) {
      short8 pa[2], vf[2];
#pragma unroll
      for (int tt = 0; tt < 2; ++tt)
        pa[tt] = *(short8*)&Pb[(th * 32 + tt * 16 + l15) * 136 + kk2 * 32 + quad * 8];
#pragma unroll
      for (int dt = 0; dt < 2; ++dt)
        vf[dt] = *(const short8*)(vT + ((size_t)((b * 16 + h) * 64 + sh * 32 + dt * 16 + l15)) * 1024 +
                                  s0 + kk2 * 32 + quad * 8);
#pragma unroll
      for (int tt = 0; tt < 2; ++tt)
#pragma unroll
        for (int dt = 0; dt < 2; ++dt)
          of[tt][dt] = MFMA(pa[tt], vf[dt], of[tt][dt]);
    }
    __syncthreads();  // B_e: Pb reads done before next-iter writes
  }

#pragma unroll
  for (int tt = 0; tt < 2; ++tt)
#pragma unroll
    for (int reg = 0; reg < 4; ++reg) {
      const int t = th * 32 + tt * 16 + quad * 4 + reg;
      const float il = 1.f / l_row[t];
#pragma unroll
      for (int dt = 0; dt < 2; ++dt) {
        const int d = sh * 32 + dt * 16 + l15;
        xb[((size_t)((t0 + t) * 4 + b)) * 1024 + h * 64 + d] = f2bf(of[tt][dt][reg] * il);
      }
    }
}

// ---------------------------------------------------------------------------
extern "C" void kernel_launch(void* const* d_in, const int* in_sizes, int n_in,
                              void* d_out, int out_size, void* d_ws, size_t ws_size,
                              hipStream_t stream) {
  const float* query   = (const float*)d_in[0];
  const float* key_    = (const float*)d_in[1];
  const float* value   = (const float*)d_in[2];
  const float* pos_emb = (const float*)d_in[3];
  const float* Wq  = (const float*)d_in[4];
  const float* bq  = (const float*)d_in[5];
  const float* Wk  = (const float*)d_in[6];
  const float* bk  = (const float*)d_in[7];
  const float* Wv  = (const float*)d_in[8];
  const float* bv  = (const float*)d_in[9];
  const float* Wp  = (const float*)d_in[10];
  const float* Wo  = (const float*)d_in[11];
  const float* bo  = (const float*)d_in[12];
  const float* pbu = (const float*)d_in[13];
  const float* pbv = (const float*)d_in[14];
  float* out = (float*)d_out;

  // workspace (ushort elements), ~69.6 MB total
  unsigned short* U = (unsigned short*)d_ws;
  unsigned short* qin = U;                   // bf16 query   (later: attn out xb)
  unsigned short* kin = U + 4194304;         // bf16 key
  unsigned short* vin = U + 8388608;         // bf16 value
  unsigned short* pe  = U + 12582912;        // bf16 pos_emb 2048 rows (later: vTb)
  unsigned short* wq  = U + 14680064;
  unsigned short* wk  = U + 15728640;
  unsigned short* wv  = U + 16777216;
  unsigned short* wp  = U + 17825792;
  unsigned short* wo  = U + 18874368;
  unsigned short* qb  = U + 19922944;        // Q proj
  unsigned short* kb  = U + 24117248;        // K proj
  unsigned short* pb  = U + 28311552;        // P proj
  unsigned short* vpo = U + 30408704;        // V proj
  unsigned short* vTb = pe;                  // aliases pe+wq+wk (dead after projections)
  unsigned short* xb  = qin;                 // attn out (qin dead after projections)
  float* fbase = (float*)(U + 34603008);
  float* uk = fbase;                         // 65536 floats
  float* vp = fbase + 65536;                 // 32768 floats

  const dim3 blk(256);

  // 1. convert everything to bf16 (one HBM-bound pass)
  convert_kernel<<<dim3(9728), blk, 0, stream>>>(
      query, key_, value, pos_emb, Wq, Wk, Wv, Wp, Wo,
      qin, kin, vin, pe, wq, wk, wv, wp, wo);

  // 2. fused Q,K,V,P projections (896 active blocks)
  GemmJobs jobs;
  jobs.j[0] = GemmJob{qin, wq, bq, qb, 32};
  jobs.j[1] = GemmJob{kin, wk, bk, kb, 32};
  jobs.j[2] = GemmJob{vin, wv, bv, vpo, 32};
  jobs.j[3] = GemmJob{pe,  wp, nullptr, pb, 16};
  gemm_qkvp<<<dim3(8, 32, 4), blk, 0, stream>>>(jobs);

  // 3. transpose V for PV MFMA B-operand (writes over dead pe/wq/wk)
  transpose_v<<<dim3(8, 16, 4), blk, 0, stream>>>(vpo, vTb);

  // 4. rank-1 bias dots
  precompute_kernel<<<dim3(384), blk, 0, stream>>>(kb, pb, pbu, pbv, uk, vp);

  // 5. fused attention (writes into dead qin buffer)
  attn_kernel<<<dim3(16, 16, 4), blk, 0, stream>>>(qb, kb, pb, vTb, uk, vp, xb);

  // 6. output projection -> fp32 d_out
  gemm_one<0><<<dim3(8, 32), blk, 0, stream>>>(xb, wo, bo, out);
}